// Round 6
// baseline (394.998 us; speedup 1.0000x reference)
//
#include <hip/hip_runtime.h>
#include <math.h>

// Problem constants
#define D_   2048
#define H_   512
#define K2D  4096
#define X_   36
#define NCOL 1152   // N * Y = 32*36

// Split-K factors (partials + fused reduce; NO atomics anywhere)
#define Z_MLP 8     // kchunk 512
#define Z_TP  4     // kchunk 512

// ws layout (float offsets):
//  A: HP1 (8x262144=2097152) -> TPP (4x1179648=4718592) -> HP2  [size 4718592]
//  TPH/TPL: tproj as bf16 hi/lo planes [16][48][2048] ushort (786432 fl each)
//  CAT: 512x4096 fp32
#define O_A    0u
#define O_TPH  4718592u
#define O_TPL  5505024u
#define O_CAT  6291456u
#define O_SB   8388608u
#define O_SO   8389120u
// total ~33.6 MB

typedef __attribute__((ext_vector_type(8))) short bf8_t;   // 8 bf16 (4 VGPRs)
typedef __attribute__((ext_vector_type(4))) float f4_t;    // MFMA accumulator

// fp32 -> bf16 round-to-nearest-even, and back
__device__ __forceinline__ unsigned short f2bf(float f) {
  unsigned u = __float_as_uint(f);
  unsigned r = u + 0x7FFFu + ((u >> 16) & 1u);
  return (unsigned short)(r >> 16);
}
__device__ __forceinline__ float bf2f(unsigned short h) {
  return __uint_as_float(((unsigned)h) << 16);
}

// split 8 fp32 into bf16 hi/lo, store k-contiguous to LDS
__device__ __forceinline__ void cvt8(unsigned short* Hp, unsigned short* Lp,
                                     float4 a, float4 b) {
  __align__(16) unsigned short h[8], l[8];
  float x[8] = {a.x, a.y, a.z, a.w, b.x, b.y, b.z, b.w};
  #pragma unroll
  for (int j = 0; j < 8; j++) {
    h[j] = f2bf(x[j]);
    l[j] = f2bf(x[j] - bf2f(h[j]));
  }
  *(bf8_t*)Hp = *(bf8_t*)&h[0];
  *(bf8_t*)Lp = *(bf8_t*)&l[0];
}

// LDS row stride for 64x64 gemm tiles: 40 ushorts (80 B)
#define TSTR 40

// ---------------------------------------------------------------------------
// Split-bf16 MFMA GEMM: Cpart[z] = A@B over z's K-chunk (fp32 in/out).
// 64x64 tile, 256 thr / 4 waves, wave tile 32x32 (2x2 frags of 16x16x32).
// Register prefetch double-buffer. amode=1: A rows = concat(fc_t[r/32], fc_d[r]).
// ---------------------------------------------------------------------------
__global__ __launch_bounds__(256, 4) void gemm_mfma64(
    const float* __restrict__ A, const float* __restrict__ A2,
    const float* __restrict__ Bm, float* __restrict__ Cpart,
    int M, int N, int K, int kchunk, int amode)
{
  __shared__ __align__(16) unsigned short AsH[64 * TSTR], AsL[64 * TSTR];
  __shared__ __align__(16) unsigned short BsH[64 * TSTR], BsL[64 * TSTR];
  const int t  = threadIdx.x;
  const int m0 = blockIdx.y << 6;
  const int n0 = blockIdx.x << 6;
  const int k0 = blockIdx.z * kchunk;
  const int kend = k0 + kchunk;
  const int w  = t >> 6;          // wave 0..3
  const int ln = t & 15;
  const int qd = (t >> 4) & 3;
  const int wm = (w >> 1) << 5;   // 0/32
  const int wn = (w & 1) << 5;    // 0/32
  const int a_row = t >> 2;            // 0..63
  const int a_kq  = (t & 3) << 3;      // 0/8/16/24
  const int b_col = t & 63;
  const int b_kq  = (t >> 6) << 3;     // 0/8/16/24

  f4_t acc[2][2];
  #pragma unroll
  for (int i = 0; i < 2; i++)
    #pragma unroll
    for (int j = 0; j < 2; j++) acc[i][j] = (f4_t)0.f;

  float4 pa0, pa1;
  float  pb[8];

  auto loadA = [&](int kb) {
    int gr = m0 + a_row;
    int gk = kb + a_kq;              // multiple of 8; never straddles 2048
    pa0 = make_float4(0.f, 0.f, 0.f, 0.f);
    pa1 = pa0;
    if (gr < M) {
      const float* src;
      if (amode == 0) src = A + (size_t)gr * K + gk;
      else src = (gk < 2048) ? (A  + ((size_t)(gr >> 5) << 11) + gk)
                             : (A2 + ((size_t)gr << 11) + (gk - 2048));
      pa0 = *(const float4*)src;
      pa1 = *(const float4*)(src + 4);
    }
  };
  auto loadB = [&](int kb) {
    #pragma unroll
    for (int j = 0; j < 8; j++)
      pb[j] = Bm[(size_t)(kb + b_kq + j) * N + n0 + b_col];
  };

  loadA(k0); loadB(k0);

  for (int kb = k0; kb < kend; kb += 32) {
    __syncthreads();
    cvt8(&AsH[a_row * TSTR + a_kq], &AsL[a_row * TSTR + a_kq], pa0, pa1);
    cvt8(&BsH[b_col * TSTR + b_kq], &BsL[b_col * TSTR + b_kq],
         make_float4(pb[0], pb[1], pb[2], pb[3]),
         make_float4(pb[4], pb[5], pb[6], pb[7]));
    __syncthreads();
    if (kb + 32 < kend) { loadA(kb + 32); loadB(kb + 32); }
    bf8_t ah[2], al[2], bh[2], bl[2];
    #pragma unroll
    for (int fm = 0; fm < 2; fm++) {
      int r = (wm + (fm << 4) + ln) * TSTR + (qd << 3);
      ah[fm] = *(const bf8_t*)&AsH[r];
      al[fm] = *(const bf8_t*)&AsL[r];
    }
    #pragma unroll
    for (int fn = 0; fn < 2; fn++) {
      int r = (wn + (fn << 4) + ln) * TSTR + (qd << 3);
      bh[fn] = *(const bf8_t*)&BsH[r];
      bl[fn] = *(const bf8_t*)&BsL[r];
    }
    #pragma unroll
    for (int fm = 0; fm < 2; fm++)
      #pragma unroll
      for (int fn = 0; fn < 2; fn++) {
        acc[fm][fn] = __builtin_amdgcn_mfma_f32_16x16x32_bf16(ah[fm], bh[fn], acc[fm][fn], 0, 0, 0);
        acc[fm][fn] = __builtin_amdgcn_mfma_f32_16x16x32_bf16(ah[fm], bl[fn], acc[fm][fn], 0, 0, 0);
        acc[fm][fn] = __builtin_amdgcn_mfma_f32_16x16x32_bf16(al[fm], bh[fn], acc[fm][fn], 0, 0, 0);
      }
  }
  // C/D layout: row = qd*4+reg, col = ln  [m89-verified]
  float* Cz = Cpart + (size_t)blockIdx.z * M * N;
  #pragma unroll
  for (int fm = 0; fm < 2; fm++) {
    #pragma unroll
    for (int reg = 0; reg < 4; reg++) {
      int gr = m0 + wm + (fm << 4) + (qd << 2) + reg;
      if (gr < M) {
        #pragma unroll
        for (int fn = 0; fn < 2; fn++)
          Cz[(size_t)gr * N + n0 + wn + (fn << 4) + ln] = acc[fm][fn][reg];
      }
    }
  }
}

// ---------------------------------------------------------------------------
// tproj z-reduce -> bf16 hi/lo planes [16][48][2048], rows 36..47 zeroed.
// One block per (b,row48).
// ---------------------------------------------------------------------------
__global__ __launch_bounds__(256) void reduce_tp_bf(
    const float* __restrict__ tpp, unsigned short* __restrict__ tph,
    unsigned short* __restrict__ tpl)
{
  int blk = blockIdx.x;          // 16*48
  int b = blk / 48, row = blk - b * 48;
  int t = threadIdx.x;
  size_t obase = (size_t)(b * 48 + row) * 2048;
  if (row < X_) {
    size_t ibase = (size_t)(b * X_ + row) * 2048;
    #pragma unroll
    for (int q = 0; q < 8; q++) {
      int c = t + (q << 8);
      float v = tpp[ibase + c];
      #pragma unroll
      for (int z = 1; z < Z_TP; z++) v += tpp[(size_t)z * 1179648 + ibase + c];
      unsigned short h = f2bf(v);
      tph[obase + c] = h;
      tpl[obase + c] = f2bf(v - bf2f(h));
    }
  } else {
    #pragma unroll
    for (int q = 0; q < 8; q++) {
      int c = t + (q << 8);
      tph[obase + c] = 0; tpl[obase + c] = 0;
    }
  }
}

// LDS row stride inside fused_si: 136 ushorts (68 dwords) -> frag reads 2-way
#define SROW 136

// ---------------------------------------------------------------------------
// Fused per-(b,i): S = tproj[b] @ att_d[b,i]^T (split-bf16 MFMA, waves split
// K 4x512, cross-wave LDS reduce) -> mask -> row/col max -> 2 softmaxes ->
// weighted feats -> cat[bi]. att_d staged once; PV re-read is L2-hot.
// ---------------------------------------------------------------------------
__global__ __launch_bounds__(256, 2) void fused_si(
    const unsigned short* __restrict__ tph, const unsigned short* __restrict__ tpl,
    const float* __restrict__ attd, const int* __restrict__ amt,
    const int* __restrict__ amd, const float* __restrict__ attt,
    float* __restrict__ cat)
{
  __shared__ __align__(16) char sbuf[4 * 48 * SROW * 2];   // 52224 B, overlaid
  __shared__ float Sm[36 * 37];
  __shared__ int   mtv[36], mdv[36];
  __shared__ float mrow[36], mcol[36], twl[36], dwl[36];
  unsigned short* AH = (unsigned short*)sbuf;
  unsigned short* AL = AH + 48 * SROW;
  unsigned short* BH = AL + 48 * SROW;
  unsigned short* BL = BH + 48 * SROW;
  const int bi = blockIdx.x, b = bi >> 5, i = bi & 31;
  const int t = threadIdx.x;
  const int w = t >> 6, ln = t & 15, qd = (t >> 4) & 3;
  if (t < 36) { mtv[t] = amt[b * 36 + t]; mdv[t] = amd[bi * 36 + t]; }

  const unsigned short* Ah = tph + (size_t)b * 48 * 2048;
  const unsigned short* Al = tpl + (size_t)b * 48 * 2048;
  const float* Bb = attd + (size_t)bi * X_ * D_;   // 36 x 2048

  f4_t acc[3][3];
  #pragma unroll
  for (int fm = 0; fm < 3; fm++)
    #pragma unroll
    for (int fn = 0; fn < 3; fn++) acc[fm][fn] = (f4_t)0.f;

  // K loop: 16 chunks of 128; wave w consumes slice [w*32, w*32+32)
  for (int c = 0; c < 16; c++) {
    int kb = c << 7;
    __syncthreads();
    #pragma unroll
    for (int j = 0; j < 3; j++) {
      int u = t + (j << 8);            // 0..767: 48 rows x 16 ushort8-slots
      int row = u >> 4, ks = (u & 15) << 3;
      *(bf8_t*)&AH[row * SROW + ks] = *(const bf8_t*)&Ah[(size_t)row * 2048 + kb + ks];
      *(bf8_t*)&AL[row * SROW + ks] = *(const bf8_t*)&Al[(size_t)row * 2048 + kb + ks];
      if (row < X_) {
        const float* src = Bb + (size_t)row * D_ + kb + ks;
        cvt8(&BH[row * SROW + ks], &BL[row * SROW + ks],
             *(const float4*)src, *(const float4*)(src + 4));
      } else {
        *(bf8_t*)&BH[row * SROW + ks] = (bf8_t)(short)0;
        *(bf8_t*)&BL[row * SROW + ks] = (bf8_t)(short)0;
      }
    }
    __syncthreads();
    const int ks = (w << 5) + (qd << 3);
    bf8_t ah[3], al[3], bh[3], bl[3];
    #pragma unroll
    for (int f = 0; f < 3; f++) {
      int r = ((f << 4) + ln) * SROW + ks;
      ah[f] = *(const bf8_t*)&AH[r];
      al[f] = *(const bf8_t*)&AL[r];
      bh[f] = *(const bf8_t*)&BH[r];
      bl[f] = *(const bf8_t*)&BL[r];
    }
    #pragma unroll
    for (int fm = 0; fm < 3; fm++)
      #pragma unroll
      for (int fn = 0; fn < 3; fn++) {
        acc[fm][fn] = __builtin_amdgcn_mfma_f32_16x16x32_bf16(ah[fm], bh[fn], acc[fm][fn], 0, 0, 0);
        acc[fm][fn] = __builtin_amdgcn_mfma_f32_16x16x32_bf16(ah[fm], bl[fn], acc[fm][fn], 0, 0, 0);
        acc[fm][fn] = __builtin_amdgcn_mfma_f32_16x16x32_bf16(al[fm], bh[fn], acc[fm][fn], 0, 0, 0);
      }
  }
  // cross-wave reduce via repurposed staging LDS: 4 planes of 48x48 fp32
  __syncthreads();
  float* Sp = (float*)sbuf + w * 2304;
  #pragma unroll
  for (int fm = 0; fm < 3; fm++)
    #pragma unroll
    for (int reg = 0; reg < 4; reg++) {
      int row = (fm << 4) + (qd << 2) + reg;
      #pragma unroll
      for (int fn = 0; fn < 3; fn++)
        Sp[row * 48 + (fn << 4) + ln] = acc[fm][fn][reg];
    }
  __syncthreads();
  const float* S0 = (const float*)sbuf;
  for (int u = t; u < 2304; u += 256) {
    int row = u / 48, col = u - row * 48;
    if (row < X_ && col < X_) {
      float v = S0[u] + S0[u + 2304] + S0[u + 4608] + S0[u + 6912];
      Sm[row * 37 + col] = (mtv[row] != 0 && mdv[col] != 0) ? v : -1e9f;
    }
  }
  __syncthreads();
  if (t < 36) {
    float r = -INFINITY, c = -INFINITY;
    for (int k = 0; k < 36; k++) {
      r = fmaxf(r, Sm[t * 37 + k]);
      c = fmaxf(c, Sm[k * 37 + t]);
    }
    mrow[t] = r; mcol[t] = c;
  }
  __syncthreads();
  if (t < 64) {           // wave 0: softmax(row-max) -> tw
    float v = (t < 36) ? mrow[t] : -INFINITY;
    float m = v;
    #pragma unroll
    for (int off = 32; off > 0; off >>= 1) m = fmaxf(m, __shfl_xor(m, off, 64));
    float e = (t < 36) ? expf(v - m) : 0.f;
    float s = e;
    #pragma unroll
    for (int off = 32; off > 0; off >>= 1) s += __shfl_xor(s, off, 64);
    if (t < 36) twl[t] = e / s;
  } else if (t < 128) {   // wave 1: softmax(col-max) -> dw
    int l = t - 64;
    float v = (l < 36) ? mcol[l] : -INFINITY;
    float m = v;
    #pragma unroll
    for (int off = 32; off > 0; off >>= 1) m = fmaxf(m, __shfl_xor(m, off, 64));
    float e = (l < 36) ? expf(v - m) : 0.f;
    float s = e;
    #pragma unroll
    for (int off = 32; off > 0; off >>= 1) s += __shfl_xor(s, off, 64);
    if (l < 36) dwl[l] = e / s;
  }
  __syncthreads();
  // weighted features -> cat (att_d[b,i] is L2-hot from staging pass)
  const float4* at4 = (const float4*)(attt + (size_t)b * X_ * D_);
  const float4* ad4 = (const float4*)(attd + (size_t)bi * X_ * D_);
  float4 t0 = make_float4(0, 0, 0, 0), t1 = t0, d0 = t0, d1 = t0;
  for (int x = 0; x < 36; x++) {
    float wt = twl[x], wd = dwl[x];
    float4 a  = at4[x * 512 + t];
    float4 a2 = at4[x * 512 + t + 256];
    float4 e  = ad4[x * 512 + t];
    float4 e2 = ad4[x * 512 + t + 256];
    t0.x = fmaf(wt, a.x, t0.x);  t0.y = fmaf(wt, a.y, t0.y);
    t0.z = fmaf(wt, a.z, t0.z);  t0.w = fmaf(wt, a.w, t0.w);
    t1.x = fmaf(wt, a2.x, t1.x); t1.y = fmaf(wt, a2.y, t1.y);
    t1.z = fmaf(wt, a2.z, t1.z); t1.w = fmaf(wt, a2.w, t1.w);
    d0.x = fmaf(wd, e.x, d0.x);  d0.y = fmaf(wd, e.y, d0.y);
    d0.z = fmaf(wd, e.z, d0.z);  d0.w = fmaf(wd, e.w, d0.w);
    d1.x = fmaf(wd, e2.x, d1.x); d1.y = fmaf(wd, e2.y, d1.y);
    d1.z = fmaf(wd, e2.z, d1.z); d1.w = fmaf(wd, e2.w, d1.w);
  }
  float4* c4 = (float4*)(cat + (size_t)bi * K2D);
  c4[t] = t0; c4[t + 256] = t1; c4[512 + t] = d0; c4[512 + t + 256] = d1;
}

// ---------------------------------------------------------------------------
// scores[row] = relu(sum_z hp[z][row,:] + b1) . W2 + b2
// ---------------------------------------------------------------------------
__global__ __launch_bounds__(256) void mlp_tail_z(
    const float* __restrict__ hp, const float* __restrict__ b1,
    const float* __restrict__ w2, const float* __restrict__ b2,
    float* __restrict__ out)
{
  int row = blockIdx.x;
  int t   = threadIdx.x;
  float v = 0.f;
  #pragma unroll
  for (int q = 0; q < 2; q++) {
    int h = t + (q << 8);
    float s = 0.f;
    #pragma unroll
    for (int z = 0; z < Z_MLP; z++)
      s += hp[(size_t)z * (H_ * 512) + (size_t)row * H_ + h];
    s += b1[h];
    v += fmaxf(s, 0.f) * w2[h];
  }
  #pragma unroll
  for (int off = 32; off > 0; off >>= 1) v += __shfl_down(v, off, 64);
  __shared__ float red[4];
  if ((t & 63) == 0) red[t >> 6] = v;
  __syncthreads();
  if (t == 0) out[row] = red[0] + red[1] + red[2] + red[3] + b2[0];
}

// ---------------------------------------------------------------------------
// out[b,:] = log_softmax(sb + so) over N=32
// ---------------------------------------------------------------------------
__global__ __launch_bounds__(64) void lsm(
    const float* __restrict__ sb, const float* __restrict__ so,
    float* __restrict__ out)
{
  int b = blockIdx.x, t = threadIdx.x;
  float s = (t < 32) ? sb[b * 32 + t] + so[b * 32 + t] : -INFINITY;
  float m = s;
  #pragma unroll
  for (int off = 32; off > 0; off >>= 1) m = fmaxf(m, __shfl_xor(m, off, 64));
  float e = (t < 32) ? expf(s - m) : 0.f;
  float sum = e;
  #pragma unroll
  for (int off = 32; off > 0; off >>= 1) sum += __shfl_xor(sum, off, 64);
  if (t < 32) out[b * 32 + t] = s - m - logf(sum);
}

extern "C" void kernel_launch(void* const* d_in, const int* in_sizes, int n_in,
                              void* d_out, int out_size, void* d_ws, size_t ws_size,
                              hipStream_t stream)
{
  const float* fc_t  = (const float*)d_in[0];
  const float* fc_d  = (const float*)d_in[1];
  const float* att_t = (const float*)d_in[2];
  const float* att_d = (const float*)d_in[3];
  const int*   am_t  = (const int*)d_in[4];
  const int*   am_d  = (const int*)d_in[5];
  const float* W1    = (const float*)d_in[6];
  const float* b1    = (const float*)d_in[7];
  const float* W2    = (const float*)d_in[8];
  const float* b2    = (const float*)d_in[9];
  const float* Wbil  = (const float*)d_in[10];
  const float* oW1   = (const float*)d_in[11];
  const float* ob1   = (const float*)d_in[12];
  const float* oW2   = (const float*)d_in[13];
  const float* ob2   = (const float*)d_in[14];
  float* ws  = (float*)d_ws;
  float* out = (float*)d_out;

  // 1. base scorer hidden partials: HP1[z] = concat(fc_t, fc_d) @ W1
  gemm_mfma64<<<dim3(8, 8, Z_MLP), 256, 0, stream>>>(fc_t, fc_d, W1, ws + O_A,
                                                     512, 512, 4096, 4096 / Z_MLP, 1);
  // 2. base scores
  mlp_tail_z<<<512, 256, 0, stream>>>(ws + O_A, b1, W2, b2, ws + O_SB);
  // 3. tproj partials: TPP[z] = att_t @ Wbil
  gemm_mfma64<<<dim3(32, 9, Z_TP), 256, 0, stream>>>(att_t, nullptr, Wbil, ws + O_A,
                                                     576, 2048, 2048, 2048 / Z_TP, 0);
  // 4. z-reduce tproj -> bf16 hi/lo planes (48-row padded)
  reduce_tp_bf<<<768, 256, 0, stream>>>(ws + O_A,
                                        (unsigned short*)(ws + O_TPH),
                                        (unsigned short*)(ws + O_TPL));
  // 5. fused S-GEMM + softmax + weighted feats -> CAT
  fused_si<<<512, 256, 0, stream>>>((const unsigned short*)(ws + O_TPH),
                                    (const unsigned short*)(ws + O_TPL),
                                    att_d, am_t, am_d, att_t, ws + O_CAT);
  // 6. object scorer hidden partials: HP2[z] = CAT @ oW1
  gemm_mfma64<<<dim3(8, 8, Z_MLP), 256, 0, stream>>>(ws + O_CAT, nullptr, oW1, ws + O_A,
                                                     512, 512, 4096, 4096 / Z_MLP, 0);
  // 7. object scores
  mlp_tail_z<<<512, 256, 0, stream>>>(ws + O_A, ob1, oW2, ob2, ws + O_SO);
  // 8. final log_softmax
  lsm<<<16, 64, 0, stream>>>(ws + O_SB, ws + O_SO, out);
}